// Round 15
// baseline (7213.896 us; speedup 1.0000x reference)
//
#include <hip/hip_runtime.h>
#include <hip/hip_bf16.h>

// SSNet: 2-layer flag-gated LSTM, persistent-tile MFMA implementation.
// B=16384, T=32, IN=64, H=512, OUT=19.
// R15: occupancy doubled. BW=32 rows/WG, 512 WGs, LDS ~68.25KB/WG ->
// 2 WGs/CU = 4 waves/SIMD at unchanged VGPR=128 (allocator already
// budgets 128 for 2x512thr blocks; only LDS was blocking co-residency).
// Cycle model: MFMA 16x16x32 ~19.4 cyc/SIMD; depth-2 pipeline covers
// ~300cy look-ahead < L3 latency of the thrashing weight stream; with
// 2 waves/SIMD the gap (~2ms total) was exposed - 4 waves absorb it.
// Per wave: 2 row-tiles (acc=32 regs), same merged L1(t)+L0(t+1) interval.

#define T_STEPS 32
#define IN_F    64
#define HID     512
#define OUT_F   19
#define BW      32   // batch rows per WG
#define NWG     512

typedef short bf16x8 __attribute__((ext_vector_type(8)));   // 8 bf16 = 4 VGPRs
typedef float f32x4  __attribute__((ext_vector_type(4)));

__device__ __forceinline__ float fast_sig(float x) {
    return __builtin_amdgcn_rcpf(1.0f + __expf(-x));
}
__device__ __forceinline__ float fast_tanh(float x) {
    return 1.0f - 2.0f * __builtin_amdgcn_rcpf(1.0f + __expf(2.0f * x));
}

// Light barrier: LDS hazards only (don't drain vmcnt).
#define LBAR() do { \
    asm volatile("s_waitcnt lgkmcnt(0)" ::: "memory"); \
    __builtin_amdgcn_sched_barrier(0); \
    __builtin_amdgcn_s_barrier(); \
    __builtin_amdgcn_sched_barrier(0); \
} while (0)

// 2 row-tiles x 4 gates
#define MFMA8(A0, A1, Q0, Q1, Q2, Q3) do { \
    acc[0][0] = __builtin_amdgcn_mfma_f32_16x16x32_bf16(A0, Q0, acc[0][0], 0, 0, 0); \
    acc[1][0] = __builtin_amdgcn_mfma_f32_16x16x32_bf16(A1, Q0, acc[1][0], 0, 0, 0); \
    acc[0][1] = __builtin_amdgcn_mfma_f32_16x16x32_bf16(A0, Q1, acc[0][1], 0, 0, 0); \
    acc[1][1] = __builtin_amdgcn_mfma_f32_16x16x32_bf16(A1, Q1, acc[1][1], 0, 0, 0); \
    acc[0][2] = __builtin_amdgcn_mfma_f32_16x16x32_bf16(A0, Q2, acc[0][2], 0, 0, 0); \
    acc[1][2] = __builtin_amdgcn_mfma_f32_16x16x32_bf16(A1, Q2, acc[1][2], 0, 0, 0); \
    acc[0][3] = __builtin_amdgcn_mfma_f32_16x16x32_bf16(A0, Q3, acc[0][3], 0, 0, 0); \
    acc[1][3] = __builtin_amdgcn_mfma_f32_16x16x32_bf16(A1, Q3, acc[1][3], 0, 0, 0); \
} while (0)

// Packed B layout, per 16-col block cb of the 2048 gate-cols:
//   dst[cb*(K*16) + kc*512 + l15*32 + lq*8 + e] = W[kc*32+lq*8+e + rowOff][cb*16+l15]
__global__ void wprep_kernel(const float* __restrict__ src,
                             __hip_bfloat16* __restrict__ dst,
                             int kcBits, int rowOff) {
    int idx = blockIdx.x * 256 + threadIdx.x;
    int total = 2048 << (kcBits + 5);
    if (idx >= total) return;
    int e   = idx & 7;
    int lq  = (idx >> 3) & 3;
    int l15 = (idx >> 5) & 15;
    int kc  = (idx >> 9) & ((1 << kcBits) - 1);
    int cb  = idx >> (9 + kcBits);
    int k   = kc * 32 + lq * 8 + e + rowOff;
    int col = cb * 16 + l15;
    dst[idx] = __float2bfloat16(src[(size_t)k * 2048 + col]);
}

// KC chunks, depth-2 rotated B pipeline, 2 row-tiles (stride RTS bytes).
template<int KC, int RTS>
__device__ __forceinline__ void gemm_sec2(const char* aE, const char* aO,
                                          const __hip_bfloat16* b0p,
                                          const __hip_bfloat16* b1p,
                                          const __hip_bfloat16* b2p,
                                          const __hip_bfloat16* b3p,
                                          f32x4 acc[2][4]) {
    bf16x8 pa0, pa1, pa2, pa3, pb0, pb1, pb2, pb3, a0, a1;
    pa0 = *(const bf16x8*)(b0p);
    pa1 = *(const bf16x8*)(b1p);
    pa2 = *(const bf16x8*)(b2p);
    pa3 = *(const bf16x8*)(b3p);
    #pragma unroll 1
    for (int m = 0; m < KC - 2; m += 2) {
        const int ao = (m >> 1) * 128;
        pb0 = *(const bf16x8*)(b0p + (m + 1) * 512);
        pb1 = *(const bf16x8*)(b1p + (m + 1) * 512);
        pb2 = *(const bf16x8*)(b2p + (m + 1) * 512);
        pb3 = *(const bf16x8*)(b3p + (m + 1) * 512);
        a0 = *(const bf16x8*)(aE + ao);
        a1 = *(const bf16x8*)(aE + RTS + ao);
        MFMA8(a0, a1, pa0, pa1, pa2, pa3);
        pa0 = *(const bf16x8*)(b0p + (m + 2) * 512);
        pa1 = *(const bf16x8*)(b1p + (m + 2) * 512);
        pa2 = *(const bf16x8*)(b2p + (m + 2) * 512);
        pa3 = *(const bf16x8*)(b3p + (m + 2) * 512);
        a0 = *(const bf16x8*)(aO + ao);
        a1 = *(const bf16x8*)(aO + RTS + ao);
        MFMA8(a0, a1, pb0, pb1, pb2, pb3);
    }
    {   // tail: chunks KC-2 (in pa) and KC-1
        const int ao = ((KC - 2) >> 1) * 128;
        pb0 = *(const bf16x8*)(b0p + (KC - 1) * 512);
        pb1 = *(const bf16x8*)(b1p + (KC - 1) * 512);
        pb2 = *(const bf16x8*)(b2p + (KC - 1) * 512);
        pb3 = *(const bf16x8*)(b3p + (KC - 1) * 512);
        a0 = *(const bf16x8*)(aE + ao);
        a1 = *(const bf16x8*)(aE + RTS + ao);
        MFMA8(a0, a1, pa0, pa1, pa2, pa3);
        a0 = *(const bf16x8*)(aO + ao);
        a1 = *(const bf16x8*)(aO + RTS + ao);
        MFMA8(a0, a1, pb0, pb1, pb2, pb3);
    }
}

__global__ __launch_bounds__(512, 2)
void lstm_main(const float* __restrict__ x,
               const float* __restrict__ b0v,
               const float* __restrict__ Wx1,     // row 0 = flag weights (f32)
               const float* __restrict__ b1v,
               const float* __restrict__ Wlin,
               const float* __restrict__ blin,
               const __hip_bfloat16* __restrict__ Wx0p,
               const __hip_bfloat16* __restrict__ Wh0p,
               const __hip_bfloat16* __restrict__ Wx1hp,
               const __hip_bfloat16* __restrict__ Wh1p,
               float* __restrict__ cws,
               float* __restrict__ hws,
               float* __restrict__ out)
{
    // LDS h tiles: row-major bf16, row stride 1024B, XOR-swizzle (row&7)<<4
    __shared__ __align__(16) __hip_bfloat16 h0s[BW * HID];   // 32 KB
    __shared__ __align__(16) __hip_bfloat16 h1s[BW * HID];   // 32 KB
    __shared__ __align__(16) __hip_bfloat16 xs[BW * IN_F];   // 4 KB, row stride 128B
    __shared__ float flags0[BW];   // flag(t)   -> L1(t) blend
    __shared__ float flags1[BW];   // flag(t+1) -> L0(t+1) blend

    const int tid  = threadIdx.x;
    const int lane = tid & 63;
    const int wid  = tid >> 6;      // 0..7
    const int l15  = lane & 15;
    const int lq   = lane >> 4;
    const int lq16 = lq * 16;
    const int laneoff = l15 * 32 + lq * 8;
    const int asw  = (l15 & 7) << 4;
    const int wg   = blockIdx.x;
    const size_t bbase = (size_t)wg * BW;
    const char* xsC = (const char*)xs;
    const char* h0C = (const char*)h0s;

    const int swE = lq16 ^ asw;
    const int swO = (64 + lq16) ^ asw;
    const char* ahE = h0C + l15 * 1024 + swE;
    const char* ahO = h0C + l15 * 1024 + swO;
    const int h1d = (int)((const char*)h1s - (const char*)h0s);
    const char* axE = xsC + l15 * 128 + swE;
    const char* axO = xsC + l15 * 128 + swO;

    const size_t wsWG0 = (size_t)(0 * NWG + wg) * 16384;   // floats
    const size_t wsWG1 = (size_t)(1 * NWG + wg) * 16384;

    // ---- Layer-1 phase ----
    auto do_L1 = [&](bool zstate) {
        #pragma unroll 1
        for (int sb = 0; sb < 4; ++sb) {
            const int b2 = sb * 8 + wid;
            f32x4 acc[2][4];
            { f32x4 zz = {0.f, 0.f, 0.f, 0.f};
              #pragma unroll
              for (int rt = 0; rt < 2; ++rt)
                  #pragma unroll
                  for (int g = 0; g < 4; ++g) acc[rt][g] = zz; }

            gemm_sec2<16, 16384>(ahE, ahO,
                Wx1hp + (size_t)(0 * 32 + b2) * 8192 + laneoff,
                Wx1hp + (size_t)(1 * 32 + b2) * 8192 + laneoff,
                Wx1hp + (size_t)(2 * 32 + b2) * 8192 + laneoff,
                Wx1hp + (size_t)(3 * 32 + b2) * 8192 + laneoff, acc);
            gemm_sec2<16, 16384>(ahE + h1d, ahO + h1d,
                Wh1p + (size_t)(0 * 32 + b2) * 8192 + laneoff,
                Wh1p + (size_t)(1 * 32 + b2) * 8192 + laneoff,
                Wh1p + (size_t)(2 * 32 + b2) * 8192 + laneoff,
                Wh1p + (size_t)(3 * 32 + b2) * 8192 + laneoff, acc);

            const size_t sbase = wsWG1 + (size_t)b2 * 512 + lane * 4;
            f32x4 cold[2], hold[2];
            if (!zstate) {
                #pragma unroll
                for (int rt = 0; rt < 2; ++rt) {
                    cold[rt] = __builtin_nontemporal_load((const f32x4*)(cws + sbase + rt * 256));
                    hold[rt] = *(const f32x4*)(hws + sbase + rt * 256);
                }
            } else {
                f32x4 zz = {0.f, 0.f, 0.f, 0.f};
                cold[0] = zz; cold[1] = zz; hold[0] = zz; hold[1] = zz;
            }
            const int jcol = b2 * 16 + l15;
            float bia[4], w10[4];
            #pragma unroll
            for (int g = 0; g < 4; ++g) {
                bia[g] = b1v[g * 512 + jcol];
                w10[g] = Wx1[g * 512 + jcol];
            }
            #pragma unroll
            for (int rt = 0; rt < 2; ++rt) {
                f32x4 cnew, hnew;
                #pragma unroll
                for (int r = 0; r < 4; ++r) {
                    const float f = flags0[rt * 16 + lq * 4 + r];
                    float gi = acc[rt][0][r] + bia[0] + f * w10[0];
                    float gf = acc[rt][1][r] + bia[1] + f * w10[1];
                    float gg = acc[rt][2][r] + bia[2] + f * w10[2];
                    float go = acc[rt][3][r] + bia[3] + f * w10[3];
                    float cn = fast_sig(gf) * cold[rt][r] + fast_sig(gi) * fast_tanh(gg);
                    float hn = fast_sig(go) * fast_tanh(cn);
                    cnew[r] = f * cn + (1.f - f) * cold[rt][r];
                    hnew[r] = f * hn + (1.f - f) * hold[rt][r];
                }
                __builtin_nontemporal_store(cnew, (f32x4*)(cws + sbase + rt * 256));
                *(f32x4*)(hws + sbase + rt * 256) = hnew;
            }
        }
    };

    // ---- Layer-0 phase ----
    auto do_L0 = [&](bool zstate) {
        #pragma unroll 1
        for (int sb = 0; sb < 4; ++sb) {
            const int b2 = sb * 8 + wid;
            f32x4 acc[2][4];
            { f32x4 zz = {0.f, 0.f, 0.f, 0.f};
              #pragma unroll
              for (int rt = 0; rt < 2; ++rt)
                  #pragma unroll
                  for (int g = 0; g < 4; ++g) acc[rt][g] = zz; }

            {   // x part: 2 chunks straight-line
                const __hip_bfloat16* bx0 = Wx0p + (size_t)(0 * 32 + b2) * 1024 + laneoff;
                const __hip_bfloat16* bx1 = Wx0p + (size_t)(1 * 32 + b2) * 1024 + laneoff;
                const __hip_bfloat16* bx2 = Wx0p + (size_t)(2 * 32 + b2) * 1024 + laneoff;
                const __hip_bfloat16* bx3 = Wx0p + (size_t)(3 * 32 + b2) * 1024 + laneoff;
                bf16x8 pa0 = *(const bf16x8*)(bx0);
                bf16x8 pa1 = *(const bf16x8*)(bx1);
                bf16x8 pa2 = *(const bf16x8*)(bx2);
                bf16x8 pa3 = *(const bf16x8*)(bx3);
                bf16x8 pb0 = *(const bf16x8*)(bx0 + 512);
                bf16x8 pb1 = *(const bf16x8*)(bx1 + 512);
                bf16x8 pb2 = *(const bf16x8*)(bx2 + 512);
                bf16x8 pb3 = *(const bf16x8*)(bx3 + 512);
                bf16x8 a0 = *(const bf16x8*)(axE);
                bf16x8 a1 = *(const bf16x8*)(axE + 2048);
                MFMA8(a0, a1, pa0, pa1, pa2, pa3);
                a0 = *(const bf16x8*)(axO);
                a1 = *(const bf16x8*)(axO + 2048);
                MFMA8(a0, a1, pb0, pb1, pb2, pb3);
            }
            gemm_sec2<16, 16384>(ahE, ahO,
                Wh0p + (size_t)(0 * 32 + b2) * 8192 + laneoff,
                Wh0p + (size_t)(1 * 32 + b2) * 8192 + laneoff,
                Wh0p + (size_t)(2 * 32 + b2) * 8192 + laneoff,
                Wh0p + (size_t)(3 * 32 + b2) * 8192 + laneoff, acc);

            const size_t sbase = wsWG0 + (size_t)b2 * 512 + lane * 4;
            f32x4 cold[2], hold[2];
            if (!zstate) {
                #pragma unroll
                for (int rt = 0; rt < 2; ++rt) {
                    cold[rt] = __builtin_nontemporal_load((const f32x4*)(cws + sbase + rt * 256));
                    hold[rt] = *(const f32x4*)(hws + sbase + rt * 256);
                }
            } else {
                f32x4 zz = {0.f, 0.f, 0.f, 0.f};
                cold[0] = zz; cold[1] = zz; hold[0] = zz; hold[1] = zz;
            }
            const int jcol = b2 * 16 + l15;
            float bia[4];
            #pragma unroll
            for (int g = 0; g < 4; ++g) bia[g] = b0v[g * 512 + jcol];
            #pragma unroll
            for (int rt = 0; rt < 2; ++rt) {
                f32x4 cnew, hnew;
                #pragma unroll
                for (int r = 0; r < 4; ++r) {
                    const float f = flags1[rt * 16 + lq * 4 + r];
                    float gi = acc[rt][0][r] + bia[0];
                    float gf = acc[rt][1][r] + bia[1];
                    float gg = acc[rt][2][r] + bia[2];
                    float go = acc[rt][3][r] + bia[3];
                    float cn = fast_sig(gf) * cold[rt][r] + fast_sig(gi) * fast_tanh(gg);
                    float hn = fast_sig(go) * fast_tanh(cn);
                    cnew[r] = f * cn + (1.f - f) * cold[rt][r];
                    hnew[r] = f * hn + (1.f - f) * hold[rt][r];
                }
                __builtin_nontemporal_store(cnew, (f32x4*)(cws + sbase + rt * 256));
                *(f32x4*)(hws + sbase + rt * 256) = hnew;
            }
        }
    };

    auto refill = [&](__hip_bfloat16* dst, size_t wsWG) {
        for (int i4 = tid; i4 < BW * HID / 4; i4 += 512) {
            f32x4 v = *(const f32x4*)(hws + wsWG + (size_t)i4 * 4);
            int lane2 = i4 & 63, rt2 = (i4 >> 6) & 1, b2r = i4 >> 7;
            int col2 = 2 * (b2r * 16 + (lane2 & 15));
            int rowb = rt2 * 16 + (lane2 >> 4) * 4;
            #pragma unroll
            for (int r = 0; r < 4; ++r) {
                int row = rowb + r;
                int byte = row * 1024 + (col2 ^ ((row & 7) << 4));
                *(__hip_bfloat16*)((char*)dst + byte) = __float2bfloat16(v[r]);
            }
        }
    };

    auto stage_x = [&](int tt) {
        for (int i = tid; i < BW * IN_F; i += 512) {
            int row = i >> 6, k = i & 63;
            float v = __builtin_nontemporal_load(&x[(bbase + row) * (T_STEPS * IN_F) + tt * IN_F + k]);
            int byte = row * 128 + ((2 * k) ^ ((row & 7) << 4));
            *(__hip_bfloat16*)((char*)xs + byte) = __float2bfloat16(v);
        }
    };

    // ================= prologue =================
    {
        int4 z; z.x = z.y = z.z = z.w = 0;
        int4* p0 = (int4*)h0s; int4* p1 = (int4*)h1s;
        for (int i = tid; i < BW * HID * 2 / 16; i += 512) { p0[i] = z; p1[i] = z; }
    }
    stage_x(0);
    if (tid < BW) {
        float f0 = x[(bbase + tid) * (T_STEPS * IN_F)];
        flags0[tid] = f0;
        flags1[tid] = f0;
    }
    LBAR();

    do_L0(true);               // L0(0)
    __syncthreads();
    refill(h0s, wsWG0);        // h0s <- h0(0)
    stage_x(1);
    if (tid < BW) flags1[tid] = x[(bbase + tid) * (T_STEPS * IN_F) + IN_F];
    LBAR();

    // ================= main loop: intervals t = 0..30 =================
    #pragma unroll 1
    for (int t = 0; t < T_STEPS - 1; ++t) {
        do_L1(t == 0);         // L1(t)
        do_L0(false);          // L0(t+1)
        __syncthreads();
        refill(h0s, wsWG0);    // h0s <- h0(t+1)
        refill(h1s, wsWG1);    // h1s <- h1(t)
        if (tid < BW) {
            float f1 = flags1[tid];
            flags0[tid] = f1;
            flags1[tid] = (t + 2 < T_STEPS)
                ? x[(bbase + tid) * (T_STEPS * IN_F) + (size_t)(t + 2) * IN_F] : 0.f;
        }
        if (t + 2 < T_STEPS) stage_x(t + 2);
        LBAR();
    }

    // ================= epilogue: L1(31) =================
    do_L1(false);
    __syncthreads();           // hws1 = fp32 h1(31)

    // ---- final linear from fp32 hws1: out = h1 @ Wlin + blin ----
    for (int task = tid; task < BW * OUT_F; task += 512) {
        int o   = task >> 5;     // 0..18
        int row = task & 31;
        const int base_row = (((row >> 4) & 1) << 8) + (((row >> 2) & 3) << 6) + (row & 3);
        float s = blin[o];
        const float* hp = hws + wsWG1 + base_row;
        const float* wl = Wlin + o;
        #pragma unroll 1
        for (int kb = 0; kb < 32; ++kb) {
            #pragma unroll
            for (int kl = 0; kl < 16; ++kl)
                s += hp[kb * 512 + kl * 4] * wl[(kb * 16 + kl) * OUT_F];
        }
        out[(bbase + row) * OUT_F + o] = s;
    }
}

extern "C" void kernel_launch(void* const* d_in, const int* in_sizes, int n_in,
                              void* d_out, int out_size, void* d_ws, size_t ws_size,
                              hipStream_t stream) {
    const float* x    = (const float*)d_in[0];
    const float* Wx0  = (const float*)d_in[1];
    const float* Wh0  = (const float*)d_in[2];
    const float* b0   = (const float*)d_in[3];
    const float* Wx1  = (const float*)d_in[4];
    const float* Wh1  = (const float*)d_in[5];
    const float* b1   = (const float*)d_in[6];
    const float* Wlin = (const float*)d_in[7];
    const float* blin = (const float*)d_in[8];

    // workspace carve (bytes)
    const size_t offWx0p  = 0;                       // 2048*64*2   = 262144
    const size_t offWh0p  = 262144;                  // 2048*512*2  = 2097152
    const size_t offWx1hp = 2359296;
    const size_t offWh1p  = 4456448;
    const size_t offC     = 6553600;                 // 2*512*16384*4 = 67108864
    const size_t offH     = 73662464;                // 67108864
    const size_t needed   = 140771328;
    if (ws_size < needed) return;

    char* w = (char*)d_ws;
    __hip_bfloat16* Wx0p  = (__hip_bfloat16*)(w + offWx0p);
    __hip_bfloat16* Wh0p  = (__hip_bfloat16*)(w + offWh0p);
    __hip_bfloat16* Wx1hp = (__hip_bfloat16*)(w + offWx1hp);
    __hip_bfloat16* Wh1p  = (__hip_bfloat16*)(w + offWh1p);
    float* cws = (float*)(w + offC);
    float* hws = (float*)(w + offH);

    dim3 blk(256);
    wprep_kernel<<<(2048 * 64 + 255) / 256, blk, 0, stream>>>(Wx0, Wx0p, 1, 0);
    wprep_kernel<<<(2048 * 512 + 255) / 256, blk, 0, stream>>>(Wh0, Wh0p, 4, 0);
    wprep_kernel<<<(2048 * 512 + 255) / 256, blk, 0, stream>>>(Wx1, Wx1hp, 4, 1);  // skip flag row
    wprep_kernel<<<(2048 * 512 + 255) / 256, blk, 0, stream>>>(Wh1, Wh1p, 4, 0);

    lstm_main<<<NWG, 512, 0, stream>>>(x, b0, Wx1, b1, Wlin, blin,
                                       Wx0p, Wh0p, Wx1hp, Wh1p, cws, hws, (float*)d_out);
}

// Round 16
// 6672.834 us; speedup vs baseline: 1.0811x; 1.0811x over previous
//
#include <hip/hip_runtime.h>
#include <hip/hip_bf16.h>

// SSNet: 2-layer flag-gated LSTM, persistent-tile MFMA implementation.
// B=16384, T=32, IN=64, H=512, OUT=19.
// R16 = R11 body (BW=64, 256 WGs, 1 WG/CU) with the GEMM re-tiled for
// latency-throughput: R15's accidental experiment showed delivered cache
// BW rises with more in-flight loads (10->13.8 TB/s) => we are latency-
// queue-limited, not BW-limited. Fix: 2-row-tile waves (acc 64->32 regs)
// + depth-4 B ring (16 outstanding loads/wave, 2x R10) + rg-paired waves
// issuing identical B addresses (second wave L1-hits, no external cost).

#define T_STEPS 32
#define IN_F    64
#define HID     512
#define OUT_F   19
#define BW      64   // batch rows per WG
#define NWG     256

typedef short bf16x8 __attribute__((ext_vector_type(8)));   // 8 bf16 = 4 VGPRs
typedef float f32x4  __attribute__((ext_vector_type(4)));

__device__ __forceinline__ float fast_sig(float x) {
    return __builtin_amdgcn_rcpf(1.0f + __expf(-x));
}
__device__ __forceinline__ float fast_tanh(float x) {
    return 1.0f - 2.0f * __builtin_amdgcn_rcpf(1.0f + __expf(2.0f * x));
}

// Light barrier: LDS hazards only (don't drain vmcnt).
#define LBAR() do { \
    asm volatile("s_waitcnt lgkmcnt(0)" ::: "memory"); \
    __builtin_amdgcn_sched_barrier(0); \
    __builtin_amdgcn_s_barrier(); \
    __builtin_amdgcn_sched_barrier(0); \
} while (0)

// 2 row-tiles x 4 gates
#define MFMA8(A0, A1, Q0, Q1, Q2, Q3) do { \
    acc[0][0] = __builtin_amdgcn_mfma_f32_16x16x32_bf16(A0, Q0, acc[0][0], 0, 0, 0); \
    acc[1][0] = __builtin_amdgcn_mfma_f32_16x16x32_bf16(A1, Q0, acc[1][0], 0, 0, 0); \
    acc[0][1] = __builtin_amdgcn_mfma_f32_16x16x32_bf16(A0, Q1, acc[0][1], 0, 0, 0); \
    acc[1][1] = __builtin_amdgcn_mfma_f32_16x16x32_bf16(A1, Q1, acc[1][1], 0, 0, 0); \
    acc[0][2] = __builtin_amdgcn_mfma_f32_16x16x32_bf16(A0, Q2, acc[0][2], 0, 0, 0); \
    acc[1][2] = __builtin_amdgcn_mfma_f32_16x16x32_bf16(A1, Q2, acc[1][2], 0, 0, 0); \
    acc[0][3] = __builtin_amdgcn_mfma_f32_16x16x32_bf16(A0, Q3, acc[0][3], 0, 0, 0); \
    acc[1][3] = __builtin_amdgcn_mfma_f32_16x16x32_bf16(A1, Q3, acc[1][3], 0, 0, 0); \
} while (0)

// Packed B layout, per 16-col block cb of the 2048 gate-cols:
//   dst[cb*(K*16) + kc*512 + l15*32 + lq*8 + e] = W[kc*32+lq*8+e + rowOff][cb*16+l15]
__global__ void wprep_kernel(const float* __restrict__ src,
                             __hip_bfloat16* __restrict__ dst,
                             int kcBits, int rowOff) {
    int idx = blockIdx.x * 256 + threadIdx.x;
    int total = 2048 << (kcBits + 5);
    if (idx >= total) return;
    int e   = idx & 7;
    int lq  = (idx >> 3) & 3;
    int l15 = (idx >> 5) & 15;
    int kc  = (idx >> 9) & ((1 << kcBits) - 1);
    int cb  = idx >> (9 + kcBits);
    int k   = kc * 32 + lq * 8 + e + rowOff;
    int col = cb * 16 + l15;
    dst[idx] = __float2bfloat16(src[(size_t)k * 2048 + col]);
}

// KC chunks (KC%4==0, KC>=8), depth-4 rotated B ring, 2 row-tiles.
// aE/aO: pre-swizzled LDS bases for even/odd chunks; RTS = row-tile stride.
template<int KC, int RTS>
__device__ __forceinline__ void gemm_p4(const char* aE, const char* aO,
                                        const __hip_bfloat16* b0p,
                                        const __hip_bfloat16* b1p,
                                        const __hip_bfloat16* b2p,
                                        const __hip_bfloat16* b3p,
                                        f32x4 acc[2][4]) {
    bf16x8 q00, q01, q02, q03, q10, q11, q12, q13;
    bf16x8 q20, q21, q22, q23, q30, q31, q32, q33;
    bf16x8 a0, a1;
    // prologue: chunks 0..3 (imm offsets 0,512,1024,1536 elems)
    q00 = *(const bf16x8*)(b0p);        q01 = *(const bf16x8*)(b1p);
    q02 = *(const bf16x8*)(b2p);        q03 = *(const bf16x8*)(b3p);
    q10 = *(const bf16x8*)(b0p + 512);  q11 = *(const bf16x8*)(b1p + 512);
    q12 = *(const bf16x8*)(b2p + 512);  q13 = *(const bf16x8*)(b3p + 512);
    q20 = *(const bf16x8*)(b0p + 1024); q21 = *(const bf16x8*)(b1p + 1024);
    q22 = *(const bf16x8*)(b2p + 1024); q23 = *(const bf16x8*)(b3p + 1024);
    q30 = *(const bf16x8*)(b0p + 1536); q31 = *(const bf16x8*)(b1p + 1536);
    q32 = *(const bf16x8*)(b2p + 1536); q33 = *(const bf16x8*)(b3p + 1536);
    // load frontier: chunk 4
    const __hip_bfloat16* p0 = b0p + 2048;
    const __hip_bfloat16* p1 = b1p + 2048;
    const __hip_bfloat16* p2 = b2p + 2048;
    const __hip_bfloat16* p3 = b3p + 2048;
    #pragma unroll 1
    for (int m = 0; m < KC - 4; m += 4) {
        const int ao = (m >> 1) * 128;
        a0 = *(const bf16x8*)(aE + ao);
        a1 = *(const bf16x8*)(aE + RTS + ao);
        MFMA8(a0, a1, q00, q01, q02, q03);
        q00 = *(const bf16x8*)(p0);        q01 = *(const bf16x8*)(p1);
        q02 = *(const bf16x8*)(p2);        q03 = *(const bf16x8*)(p3);
        a0 = *(const bf16x8*)(aO + ao);
        a1 = *(const bf16x8*)(aO + RTS + ao);
        MFMA8(a0, a1, q10, q11, q12, q13);
        q10 = *(const bf16x8*)(p0 + 512);  q11 = *(const bf16x8*)(p1 + 512);
        q12 = *(const bf16x8*)(p2 + 512);  q13 = *(const bf16x8*)(p3 + 512);
        a0 = *(const bf16x8*)(aE + ao + 128);
        a1 = *(const bf16x8*)(aE + RTS + ao + 128);
        MFMA8(a0, a1, q20, q21, q22, q23);
        q20 = *(const bf16x8*)(p0 + 1024); q21 = *(const bf16x8*)(p1 + 1024);
        q22 = *(const bf16x8*)(p2 + 1024); q23 = *(const bf16x8*)(p3 + 1024);
        a0 = *(const bf16x8*)(aO + ao + 128);
        a1 = *(const bf16x8*)(aO + RTS + ao + 128);
        MFMA8(a0, a1, q30, q31, q32, q33);
        q30 = *(const bf16x8*)(p0 + 1536); q31 = *(const bf16x8*)(p1 + 1536);
        q32 = *(const bf16x8*)(p2 + 1536); q33 = *(const bf16x8*)(p3 + 1536);
        p0 += 2048; p1 += 2048; p2 += 2048; p3 += 2048;
    }
    {   // epilogue: chunks KC-4..KC-1 (already in ring)
        const int ao = ((KC - 4) >> 1) * 128;
        a0 = *(const bf16x8*)(aE + ao);
        a1 = *(const bf16x8*)(aE + RTS + ao);
        MFMA8(a0, a1, q00, q01, q02, q03);
        a0 = *(const bf16x8*)(aO + ao);
        a1 = *(const bf16x8*)(aO + RTS + ao);
        MFMA8(a0, a1, q10, q11, q12, q13);
        a0 = *(const bf16x8*)(aE + ao + 128);
        a1 = *(const bf16x8*)(aE + RTS + ao + 128);
        MFMA8(a0, a1, q20, q21, q22, q23);
        a0 = *(const bf16x8*)(aO + ao + 128);
        a1 = *(const bf16x8*)(aO + RTS + ao + 128);
        MFMA8(a0, a1, q30, q31, q32, q33);
    }
}

__global__ __launch_bounds__(512, 2)
void lstm_main(const float* __restrict__ x,
               const float* __restrict__ b0v,
               const float* __restrict__ Wx1,     // row 0 = flag weights (f32)
               const float* __restrict__ b1v,
               const float* __restrict__ Wlin,
               const float* __restrict__ blin,
               const __hip_bfloat16* __restrict__ Wx0p,
               const __hip_bfloat16* __restrict__ Wh0p,
               const __hip_bfloat16* __restrict__ Wx1hp,
               const __hip_bfloat16* __restrict__ Wh1p,
               float* __restrict__ cws,
               float* __restrict__ hws,
               float* __restrict__ out)
{
    // LDS h tiles: row-major bf16, row stride 1024B, XOR-swizzle (row&7)<<4
    __shared__ __align__(16) __hip_bfloat16 h0s[BW * HID];   // 64 KB
    __shared__ __align__(16) __hip_bfloat16 h1s[BW * HID];   // 64 KB
    __shared__ __align__(16) __hip_bfloat16 xs[BW * IN_F];   // 8 KB, row stride 128B
    __shared__ float flags0[BW];   // flag(t)   -> L1(t) blend
    __shared__ float flags1[BW];   // flag(t+1) -> L0(t+1) blend

    const int tid  = threadIdx.x;
    const int lane = tid & 63;
    const int wid  = tid >> 6;      // 0..7
    const int rg   = wid & 1;       // 2 row-groups of 32 rows (rg-pairs share B)
    const int cg   = wid >> 1;      // 4 col-groups x 8 b2-blocks
    const int l15  = lane & 15;
    const int lq   = lane >> 4;
    const int lq16 = lq * 16;
    const int laneoff = l15 * 32 + lq * 8;
    const int asw  = (l15 & 7) << 4;
    const int wg   = blockIdx.x;
    const size_t bbase = (size_t)wg * BW;
    const char* xsC = (const char*)xs;
    const char* h0C = (const char*)h0s;

    const int swE = lq16 ^ asw;
    const int swO = (64 + lq16) ^ asw;
    const char* ahE = h0C + (rg * 32 + l15) * 1024 + swE;   // row-tile 0 base
    const char* ahO = h0C + (rg * 32 + l15) * 1024 + swO;
    const int h1d = (int)((const char*)h1s - (const char*)h0s);
    const char* axE = xsC + (rg * 32 + l15) * 128 + swE;
    const char* axO = xsC + (rg * 32 + l15) * 128 + swO;

    const size_t wsWG0 = (size_t)(0 * NWG + wg) * 32768;   // floats
    const size_t wsWG1 = (size_t)(1 * NWG + wg) * 32768;

    // ---- Layer-1 phase: b2 = cg*8+sb, 2 row-tiles at rows rg*32.. ----
    auto do_L1 = [&](bool zstate) {
        #pragma unroll 1
        for (int sb = 0; sb < 8; ++sb) {
            const int b2 = cg * 8 + sb;
            f32x4 acc[2][4];
            { f32x4 zz = {0.f, 0.f, 0.f, 0.f};
              #pragma unroll
              for (int rt = 0; rt < 2; ++rt)
                  #pragma unroll
                  for (int g = 0; g < 4; ++g) acc[rt][g] = zz; }

            gemm_p4<16, 16384>(ahE, ahO,
                Wx1hp + (size_t)(0 * 32 + b2) * 8192 + laneoff,
                Wx1hp + (size_t)(1 * 32 + b2) * 8192 + laneoff,
                Wx1hp + (size_t)(2 * 32 + b2) * 8192 + laneoff,
                Wx1hp + (size_t)(3 * 32 + b2) * 8192 + laneoff, acc);
            gemm_p4<16, 16384>(ahE + h1d, ahO + h1d,
                Wh1p + (size_t)(0 * 32 + b2) * 8192 + laneoff,
                Wh1p + (size_t)(1 * 32 + b2) * 8192 + laneoff,
                Wh1p + (size_t)(2 * 32 + b2) * 8192 + laneoff,
                Wh1p + (size_t)(3 * 32 + b2) * 8192 + laneoff, acc);

            // state block: 1024 floats per b2 (64 rows x 16 cols); rg half
            const size_t sbase = wsWG1 + (size_t)b2 * 1024 + rg * 512 + lane * 4;
            f32x4 cold[2], hold[2];
            if (!zstate) {
                #pragma unroll
                for (int rt = 0; rt < 2; ++rt) {
                    cold[rt] = __builtin_nontemporal_load((const f32x4*)(cws + sbase + rt * 256));
                    hold[rt] = *(const f32x4*)(hws + sbase + rt * 256);
                }
            } else {
                f32x4 zz = {0.f, 0.f, 0.f, 0.f};
                cold[0] = zz; cold[1] = zz; hold[0] = zz; hold[1] = zz;
            }
            const int jcol = b2 * 16 + l15;
            float bia[4], w10[4];
            #pragma unroll
            for (int g = 0; g < 4; ++g) {
                bia[g] = b1v[g * 512 + jcol];
                w10[g] = Wx1[g * 512 + jcol];
            }
            #pragma unroll
            for (int rt = 0; rt < 2; ++rt) {
                f32x4 cnew, hnew;
                #pragma unroll
                for (int r = 0; r < 4; ++r) {
                    const float f = flags0[rg * 32 + rt * 16 + lq * 4 + r];
                    float gi = acc[rt][0][r] + bia[0] + f * w10[0];
                    float gf = acc[rt][1][r] + bia[1] + f * w10[1];
                    float gg = acc[rt][2][r] + bia[2] + f * w10[2];
                    float go = acc[rt][3][r] + bia[3] + f * w10[3];
                    float cn = fast_sig(gf) * cold[rt][r] + fast_sig(gi) * fast_tanh(gg);
                    float hn = fast_sig(go) * fast_tanh(cn);
                    cnew[r] = f * cn + (1.f - f) * cold[rt][r];
                    hnew[r] = f * hn + (1.f - f) * hold[rt][r];
                }
                __builtin_nontemporal_store(cnew, (f32x4*)(cws + sbase + rt * 256));
                *(f32x4*)(hws + sbase + rt * 256) = hnew;
            }
        }
    };

    // ---- Layer-0 phase ----
    auto do_L0 = [&](bool zstate) {
        #pragma unroll 1
        for (int sb = 0; sb < 8; ++sb) {
            const int b2 = cg * 8 + sb;
            f32x4 acc[2][4];
            { f32x4 zz = {0.f, 0.f, 0.f, 0.f};
              #pragma unroll
              for (int rt = 0; rt < 2; ++rt)
                  #pragma unroll
                  for (int g = 0; g < 4; ++g) acc[rt][g] = zz; }

            {   // x part: 2 chunks straight-line (2 row-tiles)
                const __hip_bfloat16* bx0 = Wx0p + (size_t)(0 * 32 + b2) * 1024 + laneoff;
                const __hip_bfloat16* bx1 = Wx0p + (size_t)(1 * 32 + b2) * 1024 + laneoff;
                const __hip_bfloat16* bx2 = Wx0p + (size_t)(2 * 32 + b2) * 1024 + laneoff;
                const __hip_bfloat16* bx3 = Wx0p + (size_t)(3 * 32 + b2) * 1024 + laneoff;
                bf16x8 pa0 = *(const bf16x8*)(bx0);
                bf16x8 pa1 = *(const bf16x8*)(bx1);
                bf16x8 pa2 = *(const bf16x8*)(bx2);
                bf16x8 pa3 = *(const bf16x8*)(bx3);
                bf16x8 pb0 = *(const bf16x8*)(bx0 + 512);
                bf16x8 pb1 = *(const bf16x8*)(bx1 + 512);
                bf16x8 pb2 = *(const bf16x8*)(bx2 + 512);
                bf16x8 pb3 = *(const bf16x8*)(bx3 + 512);
                bf16x8 a0 = *(const bf16x8*)(axE);
                bf16x8 a1 = *(const bf16x8*)(axE + 16 * 128);
                MFMA8(a0, a1, pa0, pa1, pa2, pa3);
                a0 = *(const bf16x8*)(axO);
                a1 = *(const bf16x8*)(axO + 16 * 128);
                MFMA8(a0, a1, pb0, pb1, pb2, pb3);
            }
            gemm_p4<16, 16384>(ahE, ahO,
                Wh0p + (size_t)(0 * 32 + b2) * 8192 + laneoff,
                Wh0p + (size_t)(1 * 32 + b2) * 8192 + laneoff,
                Wh0p + (size_t)(2 * 32 + b2) * 8192 + laneoff,
                Wh0p + (size_t)(3 * 32 + b2) * 8192 + laneoff, acc);

            const size_t sbase = wsWG0 + (size_t)b2 * 1024 + rg * 512 + lane * 4;
            f32x4 cold[2], hold[2];
            if (!zstate) {
                #pragma unroll
                for (int rt = 0; rt < 2; ++rt) {
                    cold[rt] = __builtin_nontemporal_load((const f32x4*)(cws + sbase + rt * 256));
                    hold[rt] = *(const f32x4*)(hws + sbase + rt * 256);
                }
            } else {
                f32x4 zz = {0.f, 0.f, 0.f, 0.f};
                cold[0] = zz; cold[1] = zz; hold[0] = zz; hold[1] = zz;
            }
            const int jcol = b2 * 16 + l15;
            float bia[4];
            #pragma unroll
            for (int g = 0; g < 4; ++g) bia[g] = b0v[g * 512 + jcol];
            #pragma unroll
            for (int rt = 0; rt < 2; ++rt) {
                f32x4 cnew, hnew;
                #pragma unroll
                for (int r = 0; r < 4; ++r) {
                    const float f = flags1[rg * 32 + rt * 16 + lq * 4 + r];
                    float gi = acc[rt][0][r] + bia[0];
                    float gf = acc[rt][1][r] + bia[1];
                    float gg = acc[rt][2][r] + bia[2];
                    float go = acc[rt][3][r] + bia[3];
                    float cn = fast_sig(gf) * cold[rt][r] + fast_sig(gi) * fast_tanh(gg);
                    float hn = fast_sig(go) * fast_tanh(cn);
                    cnew[r] = f * cn + (1.f - f) * cold[rt][r];
                    hnew[r] = f * hn + (1.f - f) * hold[rt][r];
                }
                __builtin_nontemporal_store(cnew, (f32x4*)(cws + sbase + rt * 256));
                *(f32x4*)(hws + sbase + rt * 256) = hnew;
            }
        }
    };

    // refill: hws layout idx = b2*1024 + rg*512 + rt*256 + lane*4 + r
    auto refill = [&](__hip_bfloat16* dst, size_t wsWG) {
        for (int i4 = tid; i4 < BW * HID / 4; i4 += 512) {
            f32x4 v = *(const f32x4*)(hws + wsWG + (size_t)i4 * 4);
            int lane2 = i4 & 63, rt2 = (i4 >> 6) & 1, rg2 = (i4 >> 7) & 1, b2r = i4 >> 8;
            int col2 = 2 * (b2r * 16 + (lane2 & 15));
            int rowb = rg2 * 32 + rt2 * 16 + (lane2 >> 4) * 4;
            #pragma unroll
            for (int r = 0; r < 4; ++r) {
                int row = rowb + r;
                int byte = row * 1024 + (col2 ^ ((row & 7) << 4));
                *(__hip_bfloat16*)((char*)dst + byte) = __float2bfloat16(v[r]);
            }
        }
    };

    auto stage_x = [&](int tt) {
        for (int i = tid; i < BW * IN_F; i += 512) {
            int row = i >> 6, k = i & 63;
            float v = __builtin_nontemporal_load(&x[(bbase + row) * (T_STEPS * IN_F) + tt * IN_F + k]);
            int byte = row * 128 + ((2 * k) ^ ((row & 7) << 4));
            *(__hip_bfloat16*)((char*)xs + byte) = __float2bfloat16(v);
        }
    };

    // ================= prologue =================
    {
        int4 z; z.x = z.y = z.z = z.w = 0;
        int4* p0 = (int4*)h0s; int4* p1 = (int4*)h1s;
        for (int i = tid; i < BW * HID * 2 / 16; i += 512) { p0[i] = z; p1[i] = z; }
    }
    stage_x(0);
    if (tid < BW) {
        float f0 = x[(bbase + tid) * (T_STEPS * IN_F)];
        flags0[tid] = f0;
        flags1[tid] = f0;
    }
    LBAR();

    do_L0(true);               // L0(0)
    __syncthreads();
    refill(h0s, wsWG0);        // h0s <- h0(0)
    stage_x(1);
    if (tid < BW) flags1[tid] = x[(bbase + tid) * (T_STEPS * IN_F) + IN_F];
    LBAR();

    // ================= main loop: intervals t = 0..30 =================
    #pragma unroll 1
    for (int t = 0; t < T_STEPS - 1; ++t) {
        do_L1(t == 0);         // L1(t): h0s=h0(t), h1s=h1(t-1), flags0=flag(t)
        do_L0(false);          // L0(t+1): xs=x(t+1), h0s=h0(t), flags1=flag(t+1)
        __syncthreads();
        refill(h0s, wsWG0);    // h0s <- h0(t+1)
        refill(h1s, wsWG1);    // h1s <- h1(t)
        if (tid < BW) {
            float f1 = flags1[tid];
            flags0[tid] = f1;
            flags1[tid] = (t + 2 < T_STEPS)
                ? x[(bbase + tid) * (T_STEPS * IN_F) + (size_t)(t + 2) * IN_F] : 0.f;
        }
        if (t + 2 < T_STEPS) stage_x(t + 2);
        LBAR();
    }

    // ================= epilogue: L1(31) =================
    do_L1(false);
    __syncthreads();           // hws1 = fp32 h1(31)

    // ---- final linear from fp32 hws1: out = h1 @ Wlin + blin ----
    for (int task = tid; task < BW * OUT_F; task += 512) {
        int o   = task >> 6;     // 0..18, wave-uniform
        int row = task & 63;
        const int base_row = ((row >> 5) & 1) * 512 + ((row >> 4) & 1) * 256
                           + ((row >> 2) & 3) * 64 + (row & 3);
        float s = blin[o];
        const float* hp = hws + wsWG1 + base_row;
        const float* wl = Wlin + o;
        #pragma unroll 1
        for (int kb = 0; kb < 32; ++kb) {
            #pragma unroll
            for (int kl = 0; kl < 16; ++kl)
                s += hp[kb * 1024 + kl * 4] * wl[(kb * 16 + kl) * OUT_F];
        }
        out[(bbase + row) * OUT_F + o] = s;
    }
}

extern "C" void kernel_launch(void* const* d_in, const int* in_sizes, int n_in,
                              void* d_out, int out_size, void* d_ws, size_t ws_size,
                              hipStream_t stream) {
    const float* x    = (const float*)d_in[0];
    const float* Wx0  = (const float*)d_in[1];
    const float* Wh0  = (const float*)d_in[2];
    const float* b0   = (const float*)d_in[3];
    const float* Wx1  = (const float*)d_in[4];
    const float* Wh1  = (const float*)d_in[5];
    const float* b1   = (const float*)d_in[6];
    const float* Wlin = (const float*)d_in[7];
    const float* blin = (const float*)d_in[8];

    // workspace carve (bytes)
    const size_t offWx0p  = 0;                       // 2048*64*2   = 262144
    const size_t offWh0p  = 262144;                  // 2048*512*2  = 2097152
    const size_t offWx1hp = 2359296;
    const size_t offWh1p  = 4456448;
    const size_t offC     = 6553600;                 // 2*256*32768*4 = 67108864
    const size_t offH     = 73662464;                // 67108864
    const size_t needed   = 140771328;
    if (ws_size < needed) return;

    char* w = (char*)d_ws;
    __hip_bfloat16* Wx0p  = (__hip_bfloat16*)(w + offWx0p);
    __hip_bfloat16* Wh0p  = (__hip_bfloat16*)(w + offWh0p);
    __hip_bfloat16* Wx1hp = (__hip_bfloat16*)(w + offWx1hp);
    __hip_bfloat16* Wh1p  = (__hip_bfloat16*)(w + offWh1p);
    float* cws = (float*)(w + offC);
    float* hws = (float*)(w + offH);

    dim3 blk(256);
    wprep_kernel<<<(2048 * 64 + 255) / 256, blk, 0, stream>>>(Wx0, Wx0p, 1, 0);
    wprep_kernel<<<(2048 * 512 + 255) / 256, blk, 0, stream>>>(Wh0, Wh0p, 4, 0);
    wprep_kernel<<<(2048 * 512 + 255) / 256, blk, 0, stream>>>(Wx1, Wx1hp, 4, 1);  // skip flag row
    wprep_kernel<<<(2048 * 512 + 255) / 256, blk, 0, stream>>>(Wh1, Wh1p, 4, 0);

    lstm_main<<<NWG, 512, 0, stream>>>(x, b0, Wx1, b1, Wlin, blin,
                                       Wx0p, Wh0p, Wx1hp, Wh1p, cws, hws, (float*)d_out);
}

// Round 17
// 4972.386 us; speedup vs baseline: 1.4508x; 1.3420x over previous
//
#include <hip/hip_runtime.h>
#include <hip/hip_bf16.h>

// SSNet: 2-layer flag-gated LSTM, persistent-tile MFMA implementation.
// B=16384, T=32, IN=64, H=512, OUT=19.
// R17 = revert to R10 verbatim (best measured: 4.98 ms, 690 TFLOPS).
// R11-R16 probed barrier merge, wave specialization, XCD alignment,
// stagger, batched state prefetch, 2-WG occupancy, depth-4 B ring:
// all neutral or negative. Constraints: h state must occupy 136KB LDS
// (blocks both 2-WG occupancy and LDS B-staging), 128-VGPR cap blocks
// ring depth > 2, weight working set 6.25MB > 4MB L2/XCD forces L3
// latency on the B stream. R10 is the local optimum of this structure.

#define T_STEPS 32
#define IN_F    64
#define HID     512
#define OUT_F   19
#define BW      64   // batch rows per WG

typedef short bf16x8 __attribute__((ext_vector_type(8)));   // 8 bf16 = 4 VGPRs
typedef float f32x4  __attribute__((ext_vector_type(4)));

__device__ __forceinline__ float fast_sig(float x) {
    return __builtin_amdgcn_rcpf(1.0f + __expf(-x));
}
__device__ __forceinline__ float fast_tanh(float x) {
    return 1.0f - 2.0f * __builtin_amdgcn_rcpf(1.0f + __expf(2.0f * x));
}

// Light barrier: LDS hazards only (don't drain vmcnt).
#define LBAR() do { \
    asm volatile("s_waitcnt lgkmcnt(0)" ::: "memory"); \
    __builtin_amdgcn_sched_barrier(0); \
    __builtin_amdgcn_s_barrier(); \
    __builtin_amdgcn_sched_barrier(0); \
} while (0)

// 4 row-tiles x 4 gates
#define MFMA16(A0, A1, A2, A3, Q0, Q1, Q2, Q3) do { \
    acc[0][0] = __builtin_amdgcn_mfma_f32_16x16x32_bf16(A0, Q0, acc[0][0], 0, 0, 0); \
    acc[1][0] = __builtin_amdgcn_mfma_f32_16x16x32_bf16(A1, Q0, acc[1][0], 0, 0, 0); \
    acc[2][0] = __builtin_amdgcn_mfma_f32_16x16x32_bf16(A2, Q0, acc[2][0], 0, 0, 0); \
    acc[3][0] = __builtin_amdgcn_mfma_f32_16x16x32_bf16(A3, Q0, acc[3][0], 0, 0, 0); \
    acc[0][1] = __builtin_amdgcn_mfma_f32_16x16x32_bf16(A0, Q1, acc[0][1], 0, 0, 0); \
    acc[1][1] = __builtin_amdgcn_mfma_f32_16x16x32_bf16(A1, Q1, acc[1][1], 0, 0, 0); \
    acc[2][1] = __builtin_amdgcn_mfma_f32_16x16x32_bf16(A2, Q1, acc[2][1], 0, 0, 0); \
    acc[3][1] = __builtin_amdgcn_mfma_f32_16x16x32_bf16(A3, Q1, acc[3][1], 0, 0, 0); \
    acc[0][2] = __builtin_amdgcn_mfma_f32_16x16x32_bf16(A0, Q2, acc[0][2], 0, 0, 0); \
    acc[1][2] = __builtin_amdgcn_mfma_f32_16x16x32_bf16(A1, Q2, acc[1][2], 0, 0, 0); \
    acc[2][2] = __builtin_amdgcn_mfma_f32_16x16x32_bf16(A2, Q2, acc[2][2], 0, 0, 0); \
    acc[3][2] = __builtin_amdgcn_mfma_f32_16x16x32_bf16(A3, Q2, acc[3][2], 0, 0, 0); \
    acc[0][3] = __builtin_amdgcn_mfma_f32_16x16x32_bf16(A0, Q3, acc[0][3], 0, 0, 0); \
    acc[1][3] = __builtin_amdgcn_mfma_f32_16x16x32_bf16(A1, Q3, acc[1][3], 0, 0, 0); \
    acc[2][3] = __builtin_amdgcn_mfma_f32_16x16x32_bf16(A2, Q3, acc[2][3], 0, 0, 0); \
    acc[3][3] = __builtin_amdgcn_mfma_f32_16x16x32_bf16(A3, Q3, acc[3][3], 0, 0, 0); \
} while (0)

// Packed B layout, per 16-col block cb of the 2048 gate-cols:
//   dst[cb*(K*16) + kc*512 + l15*32 + lq*8 + e] = W[kc*32+lq*8+e + rowOff][cb*16+l15]
__global__ void wprep_kernel(const float* __restrict__ src,
                             __hip_bfloat16* __restrict__ dst,
                             int kcBits, int rowOff) {
    int idx = blockIdx.x * 256 + threadIdx.x;
    int total = 2048 << (kcBits + 5);
    if (idx >= total) return;
    int e   = idx & 7;
    int lq  = (idx >> 3) & 3;
    int l15 = (idx >> 5) & 15;
    int kc  = (idx >> 9) & ((1 << kcBits) - 1);
    int cb  = idx >> (9 + kcBits);
    int k   = kc * 32 + lq * 8 + e + rowOff;
    int col = cb * 16 + l15;
    dst[idx] = __float2bfloat16(src[(size_t)k * 2048 + col]);
}

// KC chunks, depth-2 rotated B pipeline, 4 row-tiles (stride RTS bytes).
template<int KC, int RTS>
__device__ __forceinline__ void gemm_sec4(const char* aE, const char* aO,
                                          const __hip_bfloat16* b0p,
                                          const __hip_bfloat16* b1p,
                                          const __hip_bfloat16* b2p,
                                          const __hip_bfloat16* b3p,
                                          f32x4 acc[4][4]) {
    bf16x8 pa0, pa1, pa2, pa3, pb0, pb1, pb2, pb3, a0, a1, a2, a3;
    pa0 = *(const bf16x8*)(b0p);
    pa1 = *(const bf16x8*)(b1p);
    pa2 = *(const bf16x8*)(b2p);
    pa3 = *(const bf16x8*)(b3p);
    #pragma unroll 1
    for (int m = 0; m < KC - 2; m += 2) {
        const int ao = (m >> 1) * 128;
        pb0 = *(const bf16x8*)(b0p + (m + 1) * 512);
        pb1 = *(const bf16x8*)(b1p + (m + 1) * 512);
        pb2 = *(const bf16x8*)(b2p + (m + 1) * 512);
        pb3 = *(const bf16x8*)(b3p + (m + 1) * 512);
        a0 = *(const bf16x8*)(aE + ao);
        a1 = *(const bf16x8*)(aE + RTS + ao);
        a2 = *(const bf16x8*)(aE + 2 * RTS + ao);
        a3 = *(const bf16x8*)(aE + 3 * RTS + ao);
        MFMA16(a0, a1, a2, a3, pa0, pa1, pa2, pa3);
        pa0 = *(const bf16x8*)(b0p + (m + 2) * 512);
        pa1 = *(const bf16x8*)(b1p + (m + 2) * 512);
        pa2 = *(const bf16x8*)(b2p + (m + 2) * 512);
        pa3 = *(const bf16x8*)(b3p + (m + 2) * 512);
        a0 = *(const bf16x8*)(aO + ao);
        a1 = *(const bf16x8*)(aO + RTS + ao);
        a2 = *(const bf16x8*)(aO + 2 * RTS + ao);
        a3 = *(const bf16x8*)(aO + 3 * RTS + ao);
        MFMA16(a0, a1, a2, a3, pb0, pb1, pb2, pb3);
    }
    {   // tail: chunks KC-2 (in pa) and KC-1
        const int ao = ((KC - 2) >> 1) * 128;
        pb0 = *(const bf16x8*)(b0p + (KC - 1) * 512);
        pb1 = *(const bf16x8*)(b1p + (KC - 1) * 512);
        pb2 = *(const bf16x8*)(b2p + (KC - 1) * 512);
        pb3 = *(const bf16x8*)(b3p + (KC - 1) * 512);
        a0 = *(const bf16x8*)(aE + ao);
        a1 = *(const bf16x8*)(aE + RTS + ao);
        a2 = *(const bf16x8*)(aE + 2 * RTS + ao);
        a3 = *(const bf16x8*)(aE + 3 * RTS + ao);
        MFMA16(a0, a1, a2, a3, pa0, pa1, pa2, pa3);
        a0 = *(const bf16x8*)(aO + ao);
        a1 = *(const bf16x8*)(aO + RTS + ao);
        a2 = *(const bf16x8*)(aO + 2 * RTS + ao);
        a3 = *(const bf16x8*)(aO + 3 * RTS + ao);
        MFMA16(a0, a1, a2, a3, pb0, pb1, pb2, pb3);
    }
}

__global__ __launch_bounds__(512, 2)
void lstm_main(const float* __restrict__ x,
               const float* __restrict__ b0v,
               const float* __restrict__ Wx1,     // row 0 = flag weights (f32)
               const float* __restrict__ b1v,
               const float* __restrict__ Wlin,
               const float* __restrict__ blin,
               const __hip_bfloat16* __restrict__ Wx0p,
               const __hip_bfloat16* __restrict__ Wh0p,
               const __hip_bfloat16* __restrict__ Wx1hp,
               const __hip_bfloat16* __restrict__ Wh1p,
               float* __restrict__ cws,
               float* __restrict__ hws,
               float* __restrict__ out)
{
    // LDS h tiles: row-major bf16, row stride 1024B, XOR-swizzle (row&7)<<4
    __shared__ __align__(16) __hip_bfloat16 h0s[BW * HID];   // 64 KB
    __shared__ __align__(16) __hip_bfloat16 h1s[BW * HID];   // 64 KB
    __shared__ __align__(16) __hip_bfloat16 xs[BW * IN_F];   // 8 KB, row stride 128B
    __shared__ float flags[BW];

    const int tid  = threadIdx.x;
    const int lane = tid & 63;
    const int wid  = tid >> 6;      // 0..7
    const int l15  = lane & 15;
    const int lq   = lane >> 4;
    const int lq16 = lq * 16;
    const int laneoff = l15 * 32 + lq * 8;   // elems within packed 512-elem chunk
    const int asw  = (l15 & 7) << 4;
    const int wg   = blockIdx.x;
    const size_t bbase = (size_t)wg * BW;
    const char* xsC = (const char*)xs;
    const char* h0C = (const char*)h0s;

    // pre-swizzled A bases for row-tile 0 (rt offset = rt*16*rowstride)
    const int swE = lq16 ^ asw;
    const int swO = (64 + lq16) ^ asw;
    const char* ahE = h0C + l15 * 1024 + swE;
    const char* ahO = h0C + l15 * 1024 + swO;
    const int h1d = (int)((const char*)h1s - (const char*)h0s);
    const char* axE = xsC + l15 * 128 + swE;
    const char* axO = xsC + l15 * 128 + swO;

    // zero h LDS
    {
        int4 z; z.x = z.y = z.z = z.w = 0;
        int4* p0 = (int4*)h0s; int4* p1 = (int4*)h1s;
        for (int i = tid; i < BW * HID * 2 / 16; i += 512) { p0[i] = z; p1[i] = z; }
    }
    // stage x(0) + flags
    for (int i = tid; i < BW * IN_F; i += 512) {
        int row = i >> 6, k = i & 63;
        float v = __builtin_nontemporal_load(&x[(bbase + row) * (T_STEPS * IN_F) + k]);
        int byte = row * 128 + ((2 * k) ^ ((row & 7) << 4));
        *(__hip_bfloat16*)((char*)xs + byte) = __float2bfloat16(v);
    }
    if (tid < BW) flags[tid] = x[(bbase + tid) * (T_STEPS * IN_F)];
    LBAR();

    const size_t wsWG0 = (size_t)(0 * 256 + wg) * 32768;   // floats
    const size_t wsWG1 = (size_t)(1 * 256 + wg) * 32768;

    #pragma unroll 1
    for (int t = 0; t < T_STEPS; ++t) {
        // ================= Layer 0: g0 = x@Wx0 + h0@Wh0 + b0 =================
        #pragma unroll 1
        for (int sb = 0; sb < 4; ++sb) {
            const int b2 = sb * 8 + wid;     // h-col block 0..31 (wave-uniform)
            f32x4 acc[4][4];
            { f32x4 zz = {0.f, 0.f, 0.f, 0.f};
              #pragma unroll
              for (int rt = 0; rt < 4; ++rt)
                  #pragma unroll
                  for (int g = 0; g < 4; ++g) acc[rt][g] = zz; }

            // x part: 2 chunks straight-line
            {
                const __hip_bfloat16* bx0 = Wx0p + (size_t)(0 * 32 + b2) * 1024 + laneoff;
                const __hip_bfloat16* bx1 = Wx0p + (size_t)(1 * 32 + b2) * 1024 + laneoff;
                const __hip_bfloat16* bx2 = Wx0p + (size_t)(2 * 32 + b2) * 1024 + laneoff;
                const __hip_bfloat16* bx3 = Wx0p + (size_t)(3 * 32 + b2) * 1024 + laneoff;
                bf16x8 pa0 = *(const bf16x8*)(bx0);
                bf16x8 pa1 = *(const bf16x8*)(bx1);
                bf16x8 pa2 = *(const bf16x8*)(bx2);
                bf16x8 pa3 = *(const bf16x8*)(bx3);
                bf16x8 pb0 = *(const bf16x8*)(bx0 + 512);
                bf16x8 pb1 = *(const bf16x8*)(bx1 + 512);
                bf16x8 pb2 = *(const bf16x8*)(bx2 + 512);
                bf16x8 pb3 = *(const bf16x8*)(bx3 + 512);
                bf16x8 a0 = *(const bf16x8*)(axE);
                bf16x8 a1 = *(const bf16x8*)(axE + 2048);
                bf16x8 a2 = *(const bf16x8*)(axE + 4096);
                bf16x8 a3 = *(const bf16x8*)(axE + 6144);
                MFMA16(a0, a1, a2, a3, pa0, pa1, pa2, pa3);
                a0 = *(const bf16x8*)(axO);
                a1 = *(const bf16x8*)(axO + 2048);
                a2 = *(const bf16x8*)(axO + 4096);
                a3 = *(const bf16x8*)(axO + 6144);
                MFMA16(a0, a1, a2, a3, pb0, pb1, pb2, pb3);
            }
            gemm_sec4<16, 16384>(ahE, ahO,
                Wh0p + (size_t)(0 * 32 + b2) * 8192 + laneoff,
                Wh0p + (size_t)(1 * 32 + b2) * 8192 + laneoff,
                Wh0p + (size_t)(2 * 32 + b2) * 8192 + laneoff,
                Wh0p + (size_t)(3 * 32 + b2) * 8192 + laneoff, acc);

            // epilogue
            const size_t sbase = wsWG0 + (size_t)b2 * 1024 + lane * 4;
            const int jcol = b2 * 16 + l15;
            float bia[4];
            #pragma unroll
            for (int g = 0; g < 4; ++g) bia[g] = b0v[g * 512 + jcol];
            #pragma unroll
            for (int rt = 0; rt < 4; ++rt) {
                f32x4 cold, hold;
                if (t > 0) {
                    cold = __builtin_nontemporal_load((const f32x4*)(cws + sbase + rt * 256));
                    hold = *(const f32x4*)(hws + sbase + rt * 256);
                } else {
                    f32x4 zz = {0.f, 0.f, 0.f, 0.f}; cold = zz; hold = zz;
                }
                f32x4 cnew, hnew;
                #pragma unroll
                for (int r = 0; r < 4; ++r) {
                    const float f = flags[rt * 16 + lq * 4 + r];
                    float gi = acc[rt][0][r] + bia[0];
                    float gf = acc[rt][1][r] + bia[1];
                    float gg = acc[rt][2][r] + bia[2];
                    float go = acc[rt][3][r] + bia[3];
                    float cn = fast_sig(gf) * cold[r] + fast_sig(gi) * fast_tanh(gg);
                    float hn = fast_sig(go) * fast_tanh(cn);
                    cnew[r] = f * cn + (1.f - f) * cold[r];
                    hnew[r] = f * hn + (1.f - f) * hold[r];
                }
                __builtin_nontemporal_store(cnew, (f32x4*)(cws + sbase + rt * 256));
                *(f32x4*)(hws + sbase + rt * 256) = hnew;
            }
        }
        __syncthreads();   // hws complete; everyone done reading h0s/xs

        // refill h0s (bf16, swizzled) from hws
        for (int i4 = tid; i4 < BW * HID / 4; i4 += 512) {
            f32x4 v = *(const f32x4*)(hws + wsWG0 + (size_t)i4 * 4);
            int lane2 = i4 & 63, rt2 = (i4 >> 6) & 3, b2r = i4 >> 8;
            int col2 = 2 * (b2r * 16 + (lane2 & 15));
            int rowb = rt2 * 16 + (lane2 >> 4) * 4;
            #pragma unroll
            for (int r = 0; r < 4; ++r) {
                int row = rowb + r;
                int byte = row * 1024 + (col2 ^ ((row & 7) << 4));
                *(__hip_bfloat16*)((char*)h0s + byte) = __float2bfloat16(v[r]);
            }
        }
        LBAR();   // new h0s visible

        // ===== Layer 1: g1 = flag*Wx1[0] + h0_new@Wx1[1:] + h1@Wh1 + b1 =====
        #pragma unroll 1
        for (int sb = 0; sb < 4; ++sb) {
            const int b2 = sb * 8 + wid;
            f32x4 acc[4][4];
            { f32x4 zz = {0.f, 0.f, 0.f, 0.f};
              #pragma unroll
              for (int rt = 0; rt < 4; ++rt)
                  #pragma unroll
                  for (int g = 0; g < 4; ++g) acc[rt][g] = zz; }

            gemm_sec4<16, 16384>(ahE, ahO,
                Wx1hp + (size_t)(0 * 32 + b2) * 8192 + laneoff,
                Wx1hp + (size_t)(1 * 32 + b2) * 8192 + laneoff,
                Wx1hp + (size_t)(2 * 32 + b2) * 8192 + laneoff,
                Wx1hp + (size_t)(3 * 32 + b2) * 8192 + laneoff, acc);
            gemm_sec4<16, 16384>(ahE + h1d, ahO + h1d,
                Wh1p + (size_t)(0 * 32 + b2) * 8192 + laneoff,
                Wh1p + (size_t)(1 * 32 + b2) * 8192 + laneoff,
                Wh1p + (size_t)(2 * 32 + b2) * 8192 + laneoff,
                Wh1p + (size_t)(3 * 32 + b2) * 8192 + laneoff, acc);

            const size_t sbase = wsWG1 + (size_t)b2 * 1024 + lane * 4;
            const int jcol = b2 * 16 + l15;
            float bia[4], w10[4];
            #pragma unroll
            for (int g = 0; g < 4; ++g) {
                bia[g] = b1v[g * 512 + jcol];
                w10[g] = Wx1[g * 512 + jcol];
            }
            #pragma unroll
            for (int rt = 0; rt < 4; ++rt) {
                f32x4 cold, hold;
                if (t > 0) {
                    cold = __builtin_nontemporal_load((const f32x4*)(cws + sbase + rt * 256));
                    hold = *(const f32x4*)(hws + sbase + rt * 256);
                } else {
                    f32x4 zz = {0.f, 0.f, 0.f, 0.f}; cold = zz; hold = zz;
                }
                f32x4 cnew, hnew;
                #pragma unroll
                for (int r = 0; r < 4; ++r) {
                    const float f = flags[rt * 16 + lq * 4 + r];
                    float gi = acc[rt][0][r] + bia[0] + f * w10[0];
                    float gf = acc[rt][1][r] + bia[1] + f * w10[1];
                    float gg = acc[rt][2][r] + bia[2] + f * w10[2];
                    float go = acc[rt][3][r] + bia[3] + f * w10[3];
                    float cn = fast_sig(gf) * cold[r] + fast_sig(gi) * fast_tanh(gg);
                    float hn = fast_sig(go) * fast_tanh(cn);
                    cnew[r] = f * cn + (1.f - f) * cold[r];
                    hnew[r] = f * hn + (1.f - f) * hold[r];
                }
                __builtin_nontemporal_store(cnew, (f32x4*)(cws + sbase + rt * 256));
                *(f32x4*)(hws + sbase + rt * 256) = hnew;
            }
        }
        __syncthreads();   // hws(L1) complete; done reading h0s/h1s

        // refill h1s from hws; stage x(t+1) + flags
        for (int i4 = tid; i4 < BW * HID / 4; i4 += 512) {
            f32x4 v = *(const f32x4*)(hws + wsWG1 + (size_t)i4 * 4);
            int lane2 = i4 & 63, rt2 = (i4 >> 6) & 3, b2r = i4 >> 8;
            int col2 = 2 * (b2r * 16 + (lane2 & 15));
            int rowb = rt2 * 16 + (lane2 >> 4) * 4;
            #pragma unroll
            for (int r = 0; r < 4; ++r) {
                int row = rowb + r;
                int byte = row * 1024 + (col2 ^ ((row & 7) << 4));
                *(__hip_bfloat16*)((char*)h1s + byte) = __float2bfloat16(v[r]);
            }
        }
        if (t + 1 < T_STEPS) {
            for (int i = tid; i < BW * IN_F; i += 512) {
                int row = i >> 6, k = i & 63;
                float v = __builtin_nontemporal_load(&x[(bbase + row) * (T_STEPS * IN_F) + (t + 1) * IN_F + k]);
                int byte = row * 128 + ((2 * k) ^ ((row & 7) << 4));
                *(__hip_bfloat16*)((char*)xs + byte) = __float2bfloat16(v);
            }
            if (tid < BW) flags[tid] = x[(bbase + tid) * (T_STEPS * IN_F) + (t + 1) * IN_F];
        }
        __syncthreads();   // h1s/xs/flags ready for next step
    }

    // ---- final linear: out = h1 @ Wlin + blin  (64x512 @ 512x19) ----
    for (int task = tid; task < BW * OUT_F; task += 512) {
        int o   = task >> 6;     // wave-uniform
        int row = task & 63;
        float s = blin[o];
        const float* wl = Wlin + o;
        for (int k = 0; k < HID; ++k) {
            int byte = row * 1024 + ((2 * k) ^ ((row & 7) << 4));
            float hv = __bfloat162float(*(const __hip_bfloat16*)((const char*)h1s + byte));
            s += hv * wl[k * OUT_F];
        }
        out[(bbase + row) * OUT_F + o] = s;
    }
}

extern "C" void kernel_launch(void* const* d_in, const int* in_sizes, int n_in,
                              void* d_out, int out_size, void* d_ws, size_t ws_size,
                              hipStream_t stream) {
    const float* x    = (const float*)d_in[0];
    const float* Wx0  = (const float*)d_in[1];
    const float* Wh0  = (const float*)d_in[2];
    const float* b0   = (const float*)d_in[3];
    const float* Wx1  = (const float*)d_in[4];
    const float* Wh1  = (const float*)d_in[5];
    const float* b1   = (const float*)d_in[6];
    const float* Wlin = (const float*)d_in[7];
    const float* blin = (const float*)d_in[8];

    // workspace carve (bytes)
    const size_t offWx0p  = 0;                       // 2048*64*2   = 262144
    const size_t offWh0p  = 262144;                  // 2048*512*2  = 2097152
    const size_t offWx1hp = 2359296;
    const size_t offWh1p  = 4456448;
    const size_t offC     = 6553600;                 // 2*256*32768*4 = 67108864
    const size_t offH     = 73662464;                // 67108864
    const size_t needed   = 140771328;
    if (ws_size < needed) return;

    char* w = (char*)d_ws;
    __hip_bfloat16* Wx0p  = (__hip_bfloat16*)(w + offWx0p);
    __hip_bfloat16* Wh0p  = (__hip_bfloat16*)(w + offWh0p);
    __hip_bfloat16* Wx1hp = (__hip_bfloat16*)(w + offWx1hp);
    __hip_bfloat16* Wh1p  = (__hip_bfloat16*)(w + offWh1p);
    float* cws = (float*)(w + offC);
    float* hws = (float*)(w + offH);

    dim3 blk(256);
    wprep_kernel<<<(2048 * 64 + 255) / 256, blk, 0, stream>>>(Wx0, Wx0p, 1, 0);
    wprep_kernel<<<(2048 * 512 + 255) / 256, blk, 0, stream>>>(Wh0, Wh0p, 4, 0);
    wprep_kernel<<<(2048 * 512 + 255) / 256, blk, 0, stream>>>(Wx1, Wx1hp, 4, 1);  // skip flag row
    wprep_kernel<<<(2048 * 512 + 255) / 256, blk, 0, stream>>>(Wh1, Wh1p, 4, 0);

    lstm_main<<<256, 512, 0, stream>>>(x, b0, Wx1, b1, Wlin, blin,
                                       Wx0p, Wh0p, Wx1hp, Wh1p, cws, hws, (float*)d_out);
}